// Round 1
// baseline (324.947 us; speedup 1.0000x reference)
//
#include <hip/hip_runtime.h>
#include <hip/hip_bf16.h>
#include <stdint.h>

// Problem constants (from reference)
#define T_TOK 1024
#define DIN   2048
#define NOUT  8192   // 2*O
#define OSL   4096   // O per slice
#define ROWS_PAD 1408  // max padded sorted rows: 1024 + 3*127 rounded to 128
#define BM 128
#define BN 128
#define BK 32

typedef __bf16 bf16x8 __attribute__((ext_vector_type(8)));
typedef float  f32x4  __attribute__((ext_vector_type(4)));

// async global->LDS, 16B per lane; LDS dest must be wave-uniform base (lane*16 applied by HW)
__device__ __forceinline__ void gload16(const void* gp, void* lp) {
  __builtin_amdgcn_global_load_lds(
      (__attribute__((address_space(1))) void*)gp,
      (__attribute__((address_space(3))) void*)lp, 16, 0, 0);
}

// ---------------- prep: group tokens by adapter, 128-aligned regions ----------------
__global__ void prep_sort(const int* __restrict__ indices,
                          int* __restrict__ inv,   // [ROWS_PAD] sorted row -> token (-1 = pad)
                          int* __restrict__ meta)  // [0..4]=goff[0..4], [5..8]=gend[0..3]
{
  __shared__ int cnt[4], cur[4];
  const int tid = threadIdx.x;
  if (tid < 4) cnt[tid] = 0;
  __syncthreads();
  for (int t = tid; t < T_TOK; t += 256) atomicAdd(&cnt[indices[t]], 1);
  __syncthreads();
  if (tid == 0) {
    int off = 0;
    for (int a = 0; a < 4; ++a) {
      meta[a] = off;              // goff[a]
      meta[5 + a] = off + cnt[a]; // gend[a]
      cur[a] = off;
      off = (off + cnt[a] + 127) & ~127;
    }
    meta[4] = off;                // padded total end (<= 1408)
  }
  __syncthreads();
  for (int i = tid; i < ROWS_PAD; i += 256) inv[i] = -1;
  __syncthreads();
  for (int t = tid; t < T_TOK; t += 256) {
    int a = indices[t];
    int p = atomicAdd(&cur[a], 1);
    inv[p] = t;
  }
}

// ---------------- prep: fp32 -> bf16 conversion (natural + sorted/gathered) ----------------
__global__ void prep_convert(const float* __restrict__ x,
                             const int* __restrict__ inv,
                             __bf16* __restrict__ xbf,    // [T_TOK][DIN]
                             __bf16* __restrict__ xsort)  // [ROWS_PAD][DIN]
{
  const int b = blockIdx.x;
  const int d0 = threadIdx.x * 8;
  bf16x8 h;
  if (b < T_TOK) {
    const float* src = x + (size_t)b * DIN + d0;
    float4 f0 = *(const float4*)(src);
    float4 f1 = *(const float4*)(src + 4);
    h[0] = (__bf16)f0.x; h[1] = (__bf16)f0.y; h[2] = (__bf16)f0.z; h[3] = (__bf16)f0.w;
    h[4] = (__bf16)f1.x; h[5] = (__bf16)f1.y; h[6] = (__bf16)f1.z; h[7] = (__bf16)f1.w;
    *(bf16x8*)(xbf + (size_t)b * DIN + d0) = h;
  } else {
    const int row = b - T_TOK;
    const int t = inv[row];
    if (t >= 0) {
      const float* src = x + (size_t)t * DIN + d0;
      float4 f0 = *(const float4*)(src);
      float4 f1 = *(const float4*)(src + 4);
      h[0] = (__bf16)f0.x; h[1] = (__bf16)f0.y; h[2] = (__bf16)f0.z; h[3] = (__bf16)f0.w;
      h[4] = (__bf16)f1.x; h[5] = (__bf16)f1.y; h[6] = (__bf16)f1.z; h[7] = (__bf16)f1.w;
    } else {
#pragma unroll
      for (int j = 0; j < 8; ++j) h[j] = (__bf16)0.0f;
    }
    *(bf16x8*)(xsort + (size_t)row * DIN + d0) = h;
  }
}

// ---------------- base GEMM: out = xbf @ Wb^T + bias ----------------
// 128x128 tile, BK=32, 4 waves (2x2 of 64x64), 16x16x32 bf16 MFMA.
__global__ __launch_bounds__(256) void kbase(const __bf16* __restrict__ xbf,
                                             const float* __restrict__ wb,   // [NOUT][DIN] fp32
                                             const float* __restrict__ bias,
                                             float* __restrict__ out)        // [T_TOK][NOUT]
{
  __shared__ __align__(16) char smem[16384]; // A: [0,8192) = [128][32] bf16 ; B: [8192,16384)
  const int tid  = threadIdx.x;
  const int wave = tid >> 6;
  const int lane = tid & 63;
  const int quad = lane >> 4;
  const int l16  = lane & 15;
  const int wm = (wave & 1) << 6;
  const int wn = (wave >> 1) << 6;
  const int m0 = blockIdx.y * BM;
  const int n0 = blockIdx.x * BN;

  f32x4 acc[4][4];
#pragma unroll
  for (int i = 0; i < 4; ++i)
#pragma unroll
    for (int j = 0; j < 4; ++j) acc[i][j] = (f32x4)0.0f;

  // A staging (global_load_lds): 2 issues x 4KB, row = tid>>2 (+64), kchunk = (tid&3)*8
  const __bf16* ag0 = xbf + (size_t)(m0 + (tid >> 2)) * DIN + ((tid & 3) << 3);
  const __bf16* ag1 = ag0 + (size_t)64 * DIN;
  char* sa0 = smem + wave * 1024;          // wave-uniform LDS base, lane*16 applied by HW
  char* sa1 = smem + 4096 + wave * 1024;

  // B staging via registers: row = tid>>1, k-half = (tid&1)*16 floats
  const float* bg = wb + (size_t)(n0 + (tid >> 1)) * DIN + ((tid & 1) << 4);
  char* sbw = smem + 8192 + (tid >> 1) * 64 + ((tid & 1) << 5);

  for (int k0 = 0; k0 < DIN; k0 += BK) {
    gload16(ag0, sa0);
    gload16(ag1, sa1);
    float4 f0 = *(const float4*)(bg);
    float4 f1 = *(const float4*)(bg + 4);
    float4 f2 = *(const float4*)(bg + 8);
    float4 f3 = *(const float4*)(bg + 12);
    bf16x8 h0, h1;
    h0[0] = (__bf16)f0.x; h0[1] = (__bf16)f0.y; h0[2] = (__bf16)f0.z; h0[3] = (__bf16)f0.w;
    h0[4] = (__bf16)f1.x; h0[5] = (__bf16)f1.y; h0[6] = (__bf16)f1.z; h0[7] = (__bf16)f1.w;
    h1[0] = (__bf16)f2.x; h1[1] = (__bf16)f2.y; h1[2] = (__bf16)f2.z; h1[3] = (__bf16)f2.w;
    h1[4] = (__bf16)f3.x; h1[5] = (__bf16)f3.y; h1[6] = (__bf16)f3.z; h1[7] = (__bf16)f3.w;
    *(bf16x8*)(sbw)      = h0;
    *(bf16x8*)(sbw + 16) = h1;
    __syncthreads();

    bf16x8 af[4], bfr[4];
#pragma unroll
    for (int t = 0; t < 4; ++t)
      af[t] = *(const bf16x8*)(smem + (wm + t * 16 + l16) * 64 + quad * 16);
#pragma unroll
    for (int t = 0; t < 4; ++t)
      bfr[t] = *(const bf16x8*)(smem + 8192 + (wn + t * 16 + l16) * 64 + quad * 16);
#pragma unroll
    for (int mt = 0; mt < 4; ++mt)
#pragma unroll
      for (int nt = 0; nt < 4; ++nt)
        acc[mt][nt] = __builtin_amdgcn_mfma_f32_16x16x32_bf16(af[mt], bfr[nt], acc[mt][nt], 0, 0, 0);
    __syncthreads();

    ag0 += BK; ag1 += BK; bg += BK;
  }

  // epilogue: C/D layout col=lane&15, row=quad*4+reg
#pragma unroll
  for (int nt = 0; nt < 4; ++nt) {
    const int col = n0 + wn + nt * 16 + l16;
    const float bv = bias[col];
#pragma unroll
    for (int mt = 0; mt < 4; ++mt) {
      const int rowb = m0 + wm + mt * 16 + quad * 4;
      float* op = out + (size_t)rowb * NOUT + col;
#pragma unroll
      for (int r = 0; r < 4; ++r)
        op[(size_t)r * NOUT] = acc[mt][nt][r] + bv;
    }
  }
}

// ---------------- delta GEMM: out[inv[row]] += xsort @ dequant(Wq[a])^T ----------------
__global__ __launch_bounds__(256) void kdelta(
    const __bf16* __restrict__ xs,
    const int* __restrict__ qw0, const int* __restrict__ qw1,
    const int* __restrict__ qz0, const int* __restrict__ qz1,
    const float* __restrict__ sc0, const float* __restrict__ sc1,
    const int* __restrict__ inv, const int* __restrict__ meta,
    float* __restrict__ out)
{
  const int sl = blockIdx.z;            // slice 0/1
  const int m0 = blockIdx.y * BM;       // sorted-row tile start
  if (m0 >= meta[4]) return;            // beyond padded end
  int ad = 0;                           // adapter is uniform per 128-aligned tile
  if (m0 >= meta[1]) ad = 1;
  if (m0 >= meta[2]) ad = 2;
  if (m0 >= meta[3]) ad = 3;
  if (m0 >= meta[5 + ad]) return;       // tile entirely pad (safety)

  const int n0 = blockIdx.x * BN;
  const int* qw = (sl ? qw1 : qw0) + (size_t)ad * OSL * (DIN / 8);
  const int* qz = (sl ? qz1 : qz0) + ad * (OSL / 8);
  const float* sc = (sl ? sc1 : sc0) + (size_t)ad * OSL;
  const int cbase = sl * OSL;

  __shared__ __align__(16) char smem[16384];
  const int tid  = threadIdx.x;
  const int wave = tid >> 6;
  const int lane = tid & 63;
  const int quad = lane >> 4;
  const int l16  = lane & 15;
  const int wm = (wave & 1) << 6;
  const int wn = (wave >> 1) << 6;

  f32x4 acc[4][4];
#pragma unroll
  for (int i = 0; i < 4; ++i)
#pragma unroll
    for (int j = 0; j < 4; ++j) acc[i][j] = (f32x4)0.0f;

  // A staging (same as kbase, from sorted x)
  const __bf16* ag0 = xs + (size_t)(m0 + (tid >> 2)) * DIN + ((tid & 3) << 3);
  const __bf16* ag1 = ag0 + (size_t)64 * DIN;
  char* sa0 = smem + wave * 1024;
  char* sa1 = smem + 4096 + wave * 1024;

  // B staging: per-thread fixed output row o = n0 + tid>>1, two packed words per iter
  const int o_local = tid >> 1;
  const int o = n0 + o_local;
  const float s = sc[o];
  const int zwrd = qz[o >> 3];
  const float zv = (float)((zwrd >> ((o & 7) << 2)) & 0xF);
  const float mb = -s * zv;                     // w = s*q + mb
  const int* qgp = qw + (size_t)o * (DIN / 8) + ((tid & 1) << 1);
  char* sbw = smem + 8192 + o_local * 64 + ((tid & 1) << 5);

  for (int k0 = 0; k0 < DIN; k0 += BK) {
    gload16(ag0, sa0);
    gload16(ag1, sa1);
    int2 wv = *(const int2*)(qgp);
    bf16x8 h0, h1;
#pragma unroll
    for (int j = 0; j < 8; ++j)
      h0[j] = (__bf16)fmaf(s, (float)((wv.x >> (j * 4)) & 0xF), mb);
#pragma unroll
    for (int j = 0; j < 8; ++j)
      h1[j] = (__bf16)fmaf(s, (float)((wv.y >> (j * 4)) & 0xF), mb);
    *(bf16x8*)(sbw)      = h0;
    *(bf16x8*)(sbw + 16) = h1;
    __syncthreads();

    bf16x8 af[4], bfr[4];
#pragma unroll
    for (int t = 0; t < 4; ++t)
      af[t] = *(const bf16x8*)(smem + (wm + t * 16 + l16) * 64 + quad * 16);
#pragma unroll
    for (int t = 0; t < 4; ++t)
      bfr[t] = *(const bf16x8*)(smem + 8192 + (wn + t * 16 + l16) * 64 + quad * 16);
#pragma unroll
    for (int mt = 0; mt < 4; ++mt)
#pragma unroll
      for (int nt = 0; nt < 4; ++nt)
        acc[mt][nt] = __builtin_amdgcn_mfma_f32_16x16x32_bf16(af[mt], bfr[nt], acc[mt][nt], 0, 0, 0);
    __syncthreads();

    ag0 += BK; ag1 += BK; qgp += 4;
  }

  // epilogue: scatter RMW to out[token][cbase+col]; pad rows (inv<0) skipped
#pragma unroll
  for (int mt = 0; mt < 4; ++mt) {
    const int rowb = m0 + wm + mt * 16 + quad * 4;
    int tk[4];
#pragma unroll
    for (int r = 0; r < 4; ++r) tk[r] = inv[rowb + r];
#pragma unroll
    for (int nt = 0; nt < 4; ++nt) {
      const int col = cbase + n0 + wn + nt * 16 + l16;
#pragma unroll
      for (int r = 0; r < 4; ++r) {
        if (tk[r] >= 0) {
          float* p = out + (size_t)tk[r] * NOUT + col;
          *p += acc[mt][nt][r];
        }
      }
    }
  }
}

extern "C" void kernel_launch(void* const* d_in, const int* in_sizes, int n_in,
                              void* d_out, int out_size, void* d_ws, size_t ws_size,
                              hipStream_t stream) {
  const float* x    = (const float*)d_in[0];
  const float* wb   = (const float*)d_in[1];
  const float* bias = (const float*)d_in[2];
  const int*   qw0  = (const int*)d_in[3];
  const int*   qw1  = (const int*)d_in[4];
  const int*   qz0  = (const int*)d_in[5];
  const int*   qz1  = (const int*)d_in[6];
  const float* sc0  = (const float*)d_in[7];
  const float* sc1  = (const float*)d_in[8];
  const int*   indices = (const int*)d_in[11];
  float* out = (float*)d_out;

  // workspace layout (~10 MB)
  char* w = (char*)d_ws;
  __bf16* xbf   = (__bf16*)w;                                    // 1024*2048*2 = 4 MB
  __bf16* xsort = (__bf16*)(w + (size_t)T_TOK * DIN * 2);        // 1408*2048*2 = 5.5 MB
  int* inv  = (int*)(w + (size_t)T_TOK * DIN * 2 + (size_t)ROWS_PAD * DIN * 2);
  int* meta = inv + ROWS_PAD;

  prep_sort<<<1, 256, 0, stream>>>(indices, inv, meta);
  prep_convert<<<T_TOK + ROWS_PAD, 256, 0, stream>>>(x, inv, xbf, xsort);

  dim3 gb(NOUT / BN, T_TOK / BM, 1);      // 64 x 8
  kbase<<<gb, 256, 0, stream>>>(xbf, wb, bias, out);

  dim3 gd(OSL / BN, ROWS_PAD / BM, 2);    // 32 x 11 x 2
  kdelta<<<gd, 256, 0, stream>>>(xsort, qw0, qw1, qz0, qz1, sc0, sc1, inv, meta, out);
}

// Round 2
// 237.929 us; speedup vs baseline: 1.3657x; 1.3657x over previous
//
#include <hip/hip_runtime.h>
#include <hip/hip_bf16.h>
#include <stdint.h>

// Problem constants
#define T_TOK 1024
#define DIN   2048
#define NOUT  8192   // 2*O
#define OSL   4096   // O per slice
#define ROWS_PAD 1408
#define BM 128
#define BN 128
#define BK 32

typedef _Float16 f16x8 __attribute__((ext_vector_type(8)));
typedef _Float16 f16x2 __attribute__((ext_vector_type(2)));
typedef float    f32x4 __attribute__((ext_vector_type(4)));

__device__ __forceinline__ void gload16(const void* gp, void* lp) {
  __builtin_amdgcn_global_load_lds(
      (__attribute__((address_space(1))) void*)gp,
      (__attribute__((address_space(3))) void*)lp, 16, 0, 0);
}

__device__ __forceinline__ f16x2 u2h(uint32_t u) {
  union { uint32_t u; f16x2 h; } c; c.u = u; return c.h;
}

// ---------------- prep: group tokens by adapter, 128-aligned regions ----------------
__global__ void prep_sort(const int* __restrict__ indices,
                          int* __restrict__ inv,   // [ROWS_PAD] sorted row -> token (-1 = pad)
                          int* __restrict__ meta)  // [0..3]=goff, [4]=padded end, [5..8]=gend
{
  __shared__ int cnt[4], cur[4];
  const int tid = threadIdx.x;
  if (tid < 4) cnt[tid] = 0;
  __syncthreads();
  for (int t = tid; t < T_TOK; t += 256) atomicAdd(&cnt[indices[t]], 1);
  __syncthreads();
  if (tid == 0) {
    int off = 0;
    for (int a = 0; a < 4; ++a) {
      meta[a] = off;
      meta[5 + a] = off + cnt[a];
      cur[a] = off;
      off = (off + cnt[a] + 127) & ~127;
    }
    meta[4] = off;
  }
  __syncthreads();
  for (int i = tid; i < ROWS_PAD; i += 256) inv[i] = -1;
  __syncthreads();
  for (int t = tid; t < T_TOK; t += 256) {
    int a = indices[t];
    int p = atomicAdd(&cur[a], 1);
    inv[p] = t;
  }
}

// ---------------- prep: x -> fp16, sorted/gathered, k-interleaved [0,4,1,5,2,6,3,7] ----------------
__global__ void prep_x(const float* __restrict__ x, const int* __restrict__ inv,
                       _Float16* __restrict__ xs) {
  const int row = blockIdx.x;
  const int d0 = threadIdx.x * 8;
  const int t = inv[row];
  f16x8 h;
  if (t >= 0) {
    const float* src = x + (size_t)t * DIN + d0;
    float4 f0 = *(const float4*)src;
    float4 f1 = *(const float4*)(src + 4);
    h[0] = (_Float16)f0.x; h[1] = (_Float16)f1.x;
    h[2] = (_Float16)f0.y; h[3] = (_Float16)f1.y;
    h[4] = (_Float16)f0.z; h[5] = (_Float16)f1.z;
    h[6] = (_Float16)f0.w; h[7] = (_Float16)f1.w;
  } else {
#pragma unroll
    for (int j = 0; j < 8; ++j) h[j] = (_Float16)0.0f;
  }
  *(f16x8*)(xs + (size_t)row * DIN + d0) = h;
}

// ---------------- prep: Wb fp32 -> fp16, same k-interleave ----------------
__global__ void wb_prep(const float* __restrict__ wb, _Float16* __restrict__ wbh) {
  const int n = blockIdx.x;       // one block per output row (2048/8/256 == 1)
  const int k0 = threadIdx.x * 8;
  const float* src = wb + (size_t)n * DIN + k0;
  float4 f0 = *(const float4*)src;
  float4 f1 = *(const float4*)(src + 4);
  f16x8 h;
  h[0] = (_Float16)f0.x; h[1] = (_Float16)f1.x;
  h[2] = (_Float16)f0.y; h[3] = (_Float16)f1.y;
  h[4] = (_Float16)f0.z; h[5] = (_Float16)f1.z;
  h[6] = (_Float16)f0.w; h[7] = (_Float16)f1.w;
  *(f16x8*)(wbh + (size_t)n * DIN + k0) = h;
}

// ---------------- fused GEMM: out[inv[row]] = xs @ (Wb + Wd[ad])^T + bias ----------------
// 128x128 tile, BK=32, 4 waves (2x2 of 64x64), 16x16x32 f16 MFMA.
// LDS chunk positions XOR-swizzled by (row>>1)&3 -> conflict-free b128 access.
template<bool PREP>
__global__ __launch_bounds__(256) void kfused(
    const _Float16* __restrict__ xs,
    const _Float16* __restrict__ wbh,   // PREP path: fp16 interleaved Wb
    const float*    __restrict__ wbf,   // fallback: fp32 Wb
    const int* __restrict__ qw0, const int* __restrict__ qw1,
    const int* __restrict__ qz0, const int* __restrict__ qz1,
    const float* __restrict__ sc0, const float* __restrict__ sc1,
    const float* __restrict__ bias,
    const int* __restrict__ inv, const int* __restrict__ meta,
    float* __restrict__ out)
{
  const int m0 = blockIdx.y * BM;
  if (m0 >= meta[4]) return;
  int ad = 0;                           // adapter uniform per 128-aligned tile
  if (m0 >= meta[1]) ad = 1;
  if (m0 >= meta[2]) ad = 2;
  if (m0 >= meta[3]) ad = 3;
  if (m0 >= meta[5 + ad]) return;      // tile entirely pad

  const int n0 = blockIdx.x * BN;
  const int sl = n0 >> 12;             // slice (BN=128 divides OSL=4096)
  const int tid  = threadIdx.x;
  const int wave = tid >> 6;
  const int lane = tid & 63;
  const int quad = lane >> 4;
  const int l16  = lane & 15;
  const int wm = (wave & 1) << 6;
  const int wn = (wave >> 1) << 6;

  __shared__ __align__(16) char smem[16384];  // A [0,8K), B [8K,16K)

  f32x4 acc[4][4];
#pragma unroll
  for (int i = 0; i < 4; ++i)
#pragma unroll
    for (int j = 0; j < 4; ++j) acc[i][j] = (f32x4)0.0f;

  // A staging: global_load_lds; lane's stored chunk position is (tid&3),
  // so source chunk = pos ^ swz(row), swz = (row>>1)&3 = (tid>>3)&3 here.
  const int kch = (((tid & 3) ^ ((tid >> 3) & 3)) << 3);
  const _Float16* ag0 = xs + (size_t)(m0 + (tid >> 2)) * DIN + kch;
  const _Float16* ag1 = ag0 + (size_t)64 * DIN;
  char* sa0 = smem + wave * 1024;
  char* sa1 = smem + 4096 + wave * 1024;

  // B row setup: thread pair (tid&1) covers 16 weights of row o
  const int o_local = tid >> 1;
  const int o = n0 + o_local;
  const int o_sl = o & (OSL - 1);
  const int* qw = (sl ? qw1 : qw0) + ((size_t)ad * OSL + o_sl) * (DIN / 8) + ((tid & 1) << 1);
  const int zw = (sl ? qz1 : qz0)[ad * (OSL / 8) + (o_sl >> 3)];
  const float s = (sl ? sc1 : sc0)[(size_t)ad * OSL + o_sl];
  const int z = (zw >> ((o_sl & 7) << 2)) & 0xF;
  f16x2 s2; s2[0] = s2[1] = (_Float16)s;
  f16x2 k2; k2[0] = k2[1] = (_Float16)(float)(-(1024 + z));  // exact integer in fp16

  const _Float16* wbhp = nullptr;
  const float*    wbfp = nullptr;
  if (PREP) wbhp = wbh + (size_t)o * DIN + ((tid & 1) << 4);
  else      wbfp = wbf + (size_t)o * DIN + ((tid & 1) << 4);

  const int bswz = (o_local >> 1) & 3;
  char* bb = smem + 8192 + o_local * 64;
  char* bw0 = bb + (((((tid & 1) << 1)    ) ^ bswz) << 4);
  char* bw1 = bb + (((((tid & 1) << 1) | 1) ^ bswz) << 4);

  // fragment read chunk offset (same swizzle, (row>>1)&3 == (l16>>1)&3 here)
  const int qoff = ((quad ^ ((l16 >> 1) & 3)) << 4);

  for (int k0 = 0; k0 < DIN; k0 += BK) {
    gload16(ag0, sa0);
    gload16(ag1, sa1);
    int2 wv = *(const int2*)qw;

    union { f16x8 v; f16x2 p[4]; } wA, wB;
    if (PREP) {
      wA.v = *(const f16x8*)wbhp;
      wB.v = *(const f16x8*)(wbhp + 8);
    } else {
      const float4 f0 = *(const float4*)(wbfp);
      const float4 f1 = *(const float4*)(wbfp + 4);
      const float4 f2 = *(const float4*)(wbfp + 8);
      const float4 f3 = *(const float4*)(wbfp + 12);
      wA.v[0] = (_Float16)f0.x; wA.v[1] = (_Float16)f1.x;
      wA.v[2] = (_Float16)f0.y; wA.v[3] = (_Float16)f1.y;
      wA.v[4] = (_Float16)f0.z; wA.v[5] = (_Float16)f1.z;
      wA.v[6] = (_Float16)f0.w; wA.v[7] = (_Float16)f1.w;
      wB.v[0] = (_Float16)f2.x; wB.v[1] = (_Float16)f3.x;
      wB.v[2] = (_Float16)f2.y; wB.v[3] = (_Float16)f3.y;
      wB.v[4] = (_Float16)f2.z; wB.v[5] = (_Float16)f3.z;
      wB.v[6] = (_Float16)f2.w; wB.v[7] = (_Float16)f3.w;
    }

    // AWQ-style packed dequant: pair j = (n_j, n_{j+4}) -> s*(n-z) + wb
    const uint32_t wx = (uint32_t)wv.x, wy = (uint32_t)wv.y;
    union { f16x8 v; f16x2 p[4]; } h0, h1;
#pragma unroll
    for (int j = 0; j < 4; ++j) {
      uint32_t t0 = ((wx >> (4 * j)) & 0x000F000Fu) | 0x64006400u;
      uint32_t t1 = ((wy >> (4 * j)) & 0x000F000Fu) | 0x64006400u;
      h0.p[j] = (u2h(t0) + k2) * s2 + wA.p[j];
      h1.p[j] = (u2h(t1) + k2) * s2 + wB.p[j];
    }
    *(f16x8*)bw0 = h0.v;
    *(f16x8*)bw1 = h1.v;
    __syncthreads();

    f16x8 af[4], bfr[4];
#pragma unroll
    for (int t = 0; t < 4; ++t)
      af[t] = *(const f16x8*)(smem + (wm + t * 16 + l16) * 64 + qoff);
#pragma unroll
    for (int t = 0; t < 4; ++t)
      bfr[t] = *(const f16x8*)(smem + 8192 + (wn + t * 16 + l16) * 64 + qoff);
#pragma unroll
    for (int mt = 0; mt < 4; ++mt)
#pragma unroll
      for (int nt = 0; nt < 4; ++nt)
        acc[mt][nt] = __builtin_amdgcn_mfma_f32_16x16x32_f16(af[mt], bfr[nt], acc[mt][nt], 0, 0, 0);
    __syncthreads();

    ag0 += BK; ag1 += BK; qw += 4;
    if (PREP) wbhp += BK; else wbfp += BK;
  }

  // epilogue: C/D layout col=lane&15, row=quad*4+reg; scatter to out[token], +bias
#pragma unroll
  for (int mt = 0; mt < 4; ++mt) {
    const int rowb = m0 + wm + mt * 16 + quad * 4;
    int tk[4];
#pragma unroll
    for (int r = 0; r < 4; ++r) tk[r] = inv[rowb + r];
#pragma unroll
    for (int nt = 0; nt < 4; ++nt) {
      const int col = n0 + wn + nt * 16 + l16;
      const float bv = bias[col];
#pragma unroll
      for (int r = 0; r < 4; ++r) {
        if (tk[r] >= 0)
          out[(size_t)tk[r] * NOUT + col] = acc[mt][nt][r] + bv;
      }
    }
  }
}

extern "C" void kernel_launch(void* const* d_in, const int* in_sizes, int n_in,
                              void* d_out, int out_size, void* d_ws, size_t ws_size,
                              hipStream_t stream) {
  const float* x    = (const float*)d_in[0];
  const float* wb   = (const float*)d_in[1];
  const float* bias = (const float*)d_in[2];
  const int*   qw0  = (const int*)d_in[3];
  const int*   qw1  = (const int*)d_in[4];
  const int*   qz0  = (const int*)d_in[5];
  const int*   qz1  = (const int*)d_in[6];
  const float* sc0  = (const float*)d_in[7];
  const float* sc1  = (const float*)d_in[8];
  const int*   indices = (const int*)d_in[11];
  float* out = (float*)d_out;

  // workspace: xs (5.5 MB) | inv | meta | wbh (32 MB, if it fits)
  char* w = (char*)d_ws;
  _Float16* xs = (_Float16*)w;
  size_t off = (size_t)ROWS_PAD * DIN * 2;
  int* inv  = (int*)(w + off);
  int* meta = inv + ROWS_PAD;
  size_t wbh_off = (off + (size_t)ROWS_PAD * 4 + 64 + 255) & ~(size_t)255;
  _Float16* wbh = (_Float16*)(w + wbh_off);
  const bool prep = ws_size >= wbh_off + (size_t)NOUT * DIN * 2;

  prep_sort<<<1, 256, 0, stream>>>(indices, inv, meta);
  prep_x<<<ROWS_PAD, 256, 0, stream>>>(x, inv, xs);
  if (prep) wb_prep<<<NOUT, 256, 0, stream>>>(wb, wbh);

  dim3 g(NOUT / BN, ROWS_PAD / BM, 1);   // 64 x 11
  if (prep)
    kfused<true><<<g, 256, 0, stream>>>(xs, wbh, nullptr, qw0, qw1, qz0, qz1,
                                        sc0, sc1, bias, inv, meta, out);
  else
    kfused<false><<<g, 256, 0, stream>>>(xs, nullptr, wb, qw0, qw1, qz0, qz1,
                                         sc0, sc1, bias, inv, meta, out);
}

// Round 3
// 227.069 us; speedup vs baseline: 1.4311x; 1.0478x over previous
//
#include <hip/hip_runtime.h>
#include <hip/hip_bf16.h>
#include <stdint.h>

// Problem constants
#define T_TOK 1024
#define DIN   2048
#define NOUT  8192   // 2*O
#define OSL   4096   // O per slice
#define ROWS_PAD 1408
#define BM 128
#define BN 128
#define BK 32

typedef _Float16 f16x8 __attribute__((ext_vector_type(8)));
typedef _Float16 f16x2 __attribute__((ext_vector_type(2)));
typedef float    f32x4 __attribute__((ext_vector_type(4)));

__device__ __forceinline__ void gload16(const void* gp, void* lp) {
  __builtin_amdgcn_global_load_lds(
      (__attribute__((address_space(1))) void*)gp,
      (__attribute__((address_space(3))) void*)lp, 16, 0, 0);
}

__device__ __forceinline__ f16x2 u2h(uint32_t u) {
  union { uint32_t u; f16x2 h; } c; c.u = u; return c.h;
}

__device__ __forceinline__ f16x8 cvt_interleave(float4 f0, float4 f1) {
  // k-order [0,4,1,5,2,6,3,7] so packed-nibble pairs (n_j, n_{j+4}) line up
  f16x8 h;
  h[0] = (_Float16)f0.x; h[1] = (_Float16)f1.x;
  h[2] = (_Float16)f0.y; h[3] = (_Float16)f1.y;
  h[4] = (_Float16)f0.z; h[5] = (_Float16)f1.z;
  h[6] = (_Float16)f0.w; h[7] = (_Float16)f1.w;
  return h;
}

// ================= kernel 1: sort + x->fp16 + W_eff build, one launch =================
// blocks: [0] sort | [1, 1+T_TOK+1) x rows (last = zero pad row) | rest: weff/wbh rows
template<bool FULL>
__global__ void prep_all(const float* __restrict__ x, const float* __restrict__ wb,
                         const int* __restrict__ qw0, const int* __restrict__ qw1,
                         const int* __restrict__ qz0, const int* __restrict__ qz1,
                         const float* __restrict__ sc0, const float* __restrict__ sc1,
                         const int* __restrict__ indices,
                         _Float16* __restrict__ xh,    // [T_TOK+1][DIN], row T_TOK = zeros
                         _Float16* __restrict__ wout,  // FULL: weff [4][NOUT][DIN]; else wbh [NOUT][DIN]
                         int* __restrict__ inv, int* __restrict__ meta)
{
  const int b = blockIdx.x;
  const int tid = threadIdx.x;

  if (b == 0) {  // ---- token sort into 128-aligned adapter groups ----
    __shared__ int cnt[4], cur[4];
    if (tid < 4) cnt[tid] = 0;
    __syncthreads();
    for (int t = tid; t < T_TOK; t += 256) atomicAdd(&cnt[indices[t]], 1);
    __syncthreads();
    if (tid == 0) {
      int off = 0;
      for (int a = 0; a < 4; ++a) {
        meta[a] = off;
        meta[5 + a] = off + cnt[a];
        cur[a] = off;
        off = (off + cnt[a] + 127) & ~127;
      }
      meta[4] = off;
    }
    __syncthreads();
    for (int i = tid; i < ROWS_PAD; i += 256) inv[i] = -1;
    __syncthreads();
    for (int t = tid; t < T_TOK; t += 256) {
      int a = indices[t];
      int p = atomicAdd(&cur[a], 1);
      inv[p] = t;
    }
    return;
  }

  if (b <= 1 + T_TOK) {  // ---- x -> fp16, natural order, interleaved ----
    const int row = b - 1;          // 0..T_TOK (T_TOK = zero row)
    const int d0 = tid * 8;
    f16x8 h;
    if (row < T_TOK) {
      const float* src = x + (size_t)row * DIN + d0;
      h = cvt_interleave(*(const float4*)src, *(const float4*)(src + 4));
    } else {
#pragma unroll
      for (int j = 0; j < 8; ++j) h[j] = (_Float16)0.0f;
    }
    *(f16x8*)(xh + (size_t)row * DIN + d0) = h;
    return;
  }

  // ---- W_eff (or plain fp16 Wb) row n ----
  const int n = b - (2 + T_TOK);    // 0..NOUT-1
  const int d0 = tid * 8;
  const float* src = wb + (size_t)n * DIN + d0;
  union { f16x8 v; f16x2 p[4]; } wbr;
  wbr.v = cvt_interleave(*(const float4*)src, *(const float4*)(src + 4));

  if (!FULL) {
    *(f16x8*)(wout + (size_t)n * DIN + d0) = wbr.v;
    return;
  }

  const int sl = n >> 12;
  const int n_sl = n & (OSL - 1);
  const int* qw = sl ? qw1 : qw0;
  const int* qz = sl ? qz1 : qz0;
  const float* sc = sl ? sc1 : sc0;

#pragma unroll
  for (int a = 0; a < 4; ++a) {
    const uint32_t wv = (uint32_t)qw[((size_t)(a * OSL + n_sl)) * (DIN / 8) + tid];
    const int zw = qz[a * (OSL / 8) + (n_sl >> 3)];
    const float s = sc[(size_t)a * OSL + n_sl];
    const int z = (zw >> ((n_sl & 7) << 2)) & 0xF;
    f16x2 s2; s2[0] = s2[1] = (_Float16)s;
    f16x2 k2; k2[0] = k2[1] = (_Float16)(float)(-(1024 + z));
    union { f16x8 v; f16x2 p[4]; } h;
#pragma unroll
    for (int j = 0; j < 4; ++j) {
      uint32_t t0 = ((wv >> (4 * j)) & 0x000F000Fu) | 0x64006400u;
      h.p[j] = (u2h(t0) + k2) * s2 + wbr.p[j];
    }
    *(f16x8*)(wout + ((size_t)(a * NOUT) + n) * DIN + d0) = h.v;
  }
}

// ================= kernel 2 (FULL): pure MFMA GEMM on W_eff, gather-A =================
// 128x128 tile, BK=32, 4 waves (2x2 of 64x64), 16x16x32 f16 MFMA, all staging via
// global_load_lds with XOR chunk swizzle -> conflict-free ds_read_b128.
__global__ __launch_bounds__(256) void kslim(
    const _Float16* __restrict__ xh, const _Float16* __restrict__ weff,
    const float* __restrict__ bias,
    const int* __restrict__ inv, const int* __restrict__ meta,
    float* __restrict__ out)
{
  const int m0 = blockIdx.y * BM;
  if (m0 >= meta[4]) return;
  int ad = 0;
  if (m0 >= meta[1]) ad = 1;
  if (m0 >= meta[2]) ad = 2;
  if (m0 >= meta[3]) ad = 3;
  if (m0 >= meta[5 + ad]) return;      // tile entirely pad

  const int n0 = blockIdx.x * BN;
  const int tid  = threadIdx.x;
  const int wave = tid >> 6;
  const int lane = tid & 63;
  const int quad = lane >> 4;
  const int l16  = lane & 15;
  const int wm = (wave & 1) << 6;
  const int wn = (wave >> 1) << 6;

  __shared__ __align__(16) char smem[16384];  // A [0,8K), B [8K,16K)

  f32x4 acc[4][4];
#pragma unroll
  for (int i = 0; i < 4; ++i)
#pragma unroll
    for (int j = 0; j < 4; ++j) acc[i][j] = (f32x4)0.0f;

  // staged chunk position (tid&3) holds source chunk (tid&3)^((row>>1)&3)
  const int kch = (((tid & 3) ^ ((tid >> 3) & 3)) << 3);
  const int rloc = tid >> 2;
  int r0 = inv[m0 + rloc];       if (r0 < 0) r0 = T_TOK;   // pad -> zero row
  int r1 = inv[m0 + rloc + 64];  if (r1 < 0) r1 = T_TOK;
  const _Float16* ag0 = xh + (size_t)r0 * DIN + kch;
  const _Float16* ag1 = xh + (size_t)r1 * DIN + kch;
  const _Float16* bg0 = weff + ((size_t)(ad * NOUT) + n0 + rloc) * DIN + kch;
  const _Float16* bg1 = bg0 + (size_t)64 * DIN;
  char* sa0 = smem +         wave * 1024;
  char* sa1 = smem +  4096 + wave * 1024;
  char* sb0 = smem +  8192 + wave * 1024;
  char* sb1 = smem + 12288 + wave * 1024;

  const int qoff = ((quad ^ ((l16 >> 1) & 3)) << 4);

  for (int k0 = 0; k0 < DIN; k0 += BK) {
    gload16(ag0, sa0);
    gload16(ag1, sa1);
    gload16(bg0, sb0);
    gload16(bg1, sb1);
    __syncthreads();

    f16x8 af[4], bfr[4];
#pragma unroll
    for (int t = 0; t < 4; ++t)
      af[t] = *(const f16x8*)(smem + (wm + t * 16 + l16) * 64 + qoff);
#pragma unroll
    for (int t = 0; t < 4; ++t)
      bfr[t] = *(const f16x8*)(smem + 8192 + (wn + t * 16 + l16) * 64 + qoff);
#pragma unroll
    for (int mt = 0; mt < 4; ++mt)
#pragma unroll
      for (int nt = 0; nt < 4; ++nt)
        acc[mt][nt] = __builtin_amdgcn_mfma_f32_16x16x32_f16(af[mt], bfr[nt], acc[mt][nt], 0, 0, 0);
    __syncthreads();

    ag0 += BK; ag1 += BK; bg0 += BK; bg1 += BK;
  }

  // epilogue: C/D col=lane&15, row=quad*4+reg; scatter to out[token], +bias
#pragma unroll
  for (int mt = 0; mt < 4; ++mt) {
    const int rowb = m0 + wm + mt * 16 + quad * 4;
    int tk[4];
#pragma unroll
    for (int r = 0; r < 4; ++r) tk[r] = inv[rowb + r];
#pragma unroll
    for (int nt = 0; nt < 4; ++nt) {
      const int col = n0 + wn + nt * 16 + l16;
      const float bv = bias[col];
#pragma unroll
      for (int r = 0; r < 4; ++r) {
        if (tk[r] >= 0)
          out[(size_t)tk[r] * NOUT + col] = acc[mt][nt][r] + bv;
      }
    }
  }
}

// ================= kernel 2 (fallback, ws too small): in-loop dequant =================
__global__ __launch_bounds__(256) void kdq(
    const _Float16* __restrict__ xh, const _Float16* __restrict__ wbh,
    const int* __restrict__ qw0, const int* __restrict__ qw1,
    const int* __restrict__ qz0, const int* __restrict__ qz1,
    const float* __restrict__ sc0, const float* __restrict__ sc1,
    const float* __restrict__ bias,
    const int* __restrict__ inv, const int* __restrict__ meta,
    float* __restrict__ out)
{
  const int m0 = blockIdx.y * BM;
  if (m0 >= meta[4]) return;
  int ad = 0;
  if (m0 >= meta[1]) ad = 1;
  if (m0 >= meta[2]) ad = 2;
  if (m0 >= meta[3]) ad = 3;
  if (m0 >= meta[5 + ad]) return;

  const int n0 = blockIdx.x * BN;
  const int sl = n0 >> 12;
  const int tid  = threadIdx.x;
  const int wave = tid >> 6;
  const int lane = tid & 63;
  const int quad = lane >> 4;
  const int l16  = lane & 15;
  const int wm = (wave & 1) << 6;
  const int wn = (wave >> 1) << 6;

  __shared__ __align__(16) char smem[16384];

  f32x4 acc[4][4];
#pragma unroll
  for (int i = 0; i < 4; ++i)
#pragma unroll
    for (int j = 0; j < 4; ++j) acc[i][j] = (f32x4)0.0f;

  const int kch = (((tid & 3) ^ ((tid >> 3) & 3)) << 3);
  const int rloc = tid >> 2;
  int r0 = inv[m0 + rloc];       if (r0 < 0) r0 = T_TOK;
  int r1 = inv[m0 + rloc + 64];  if (r1 < 0) r1 = T_TOK;
  const _Float16* ag0 = xh + (size_t)r0 * DIN + kch;
  const _Float16* ag1 = xh + (size_t)r1 * DIN + kch;
  char* sa0 = smem + wave * 1024;
  char* sa1 = smem + 4096 + wave * 1024;

  const int o_local = tid >> 1;
  const int o = n0 + o_local;
  const int o_sl = o & (OSL - 1);
  const int* qw = (sl ? qw1 : qw0) + ((size_t)ad * OSL + o_sl) * (DIN / 8) + ((tid & 1) << 1);
  const int zw = (sl ? qz1 : qz0)[ad * (OSL / 8) + (o_sl >> 3)];
  const float s = (sl ? sc1 : sc0)[(size_t)ad * OSL + o_sl];
  const int z = (zw >> ((o_sl & 7) << 2)) & 0xF;
  f16x2 s2; s2[0] = s2[1] = (_Float16)s;
  f16x2 k2; k2[0] = k2[1] = (_Float16)(float)(-(1024 + z));
  const _Float16* wbhp = wbh + (size_t)o * DIN + ((tid & 1) << 4);

  const int bswz = (o_local >> 1) & 3;
  char* bb = smem + 8192 + o_local * 64;
  char* bw0 = bb + (((((tid & 1) << 1)    ) ^ bswz) << 4);
  char* bw1 = bb + (((((tid & 1) << 1) | 1) ^ bswz) << 4);
  const int qoff = ((quad ^ ((l16 >> 1) & 3)) << 4);

  for (int k0 = 0; k0 < DIN; k0 += BK) {
    gload16(ag0, sa0);
    gload16(ag1, sa1);
    int2 wv = *(const int2*)qw;
    union { f16x8 v; f16x2 p[4]; } wA, wB;
    wA.v = *(const f16x8*)wbhp;
    wB.v = *(const f16x8*)(wbhp + 8);
    const uint32_t wx = (uint32_t)wv.x, wy = (uint32_t)wv.y;
    union { f16x8 v; f16x2 p[4]; } h0, h1;
#pragma unroll
    for (int j = 0; j < 4; ++j) {
      uint32_t t0 = ((wx >> (4 * j)) & 0x000F000Fu) | 0x64006400u;
      uint32_t t1 = ((wy >> (4 * j)) & 0x000F000Fu) | 0x64006400u;
      h0.p[j] = (u2h(t0) + k2) * s2 + wA.p[j];
      h1.p[j] = (u2h(t1) + k2) * s2 + wB.p[j];
    }
    *(f16x8*)bw0 = h0.v;
    *(f16x8*)bw1 = h1.v;
    __syncthreads();

    f16x8 af[4], bfr[4];
#pragma unroll
    for (int t = 0; t < 4; ++t)
      af[t] = *(const f16x8*)(smem + (wm + t * 16 + l16) * 64 + qoff);
#pragma unroll
    for (int t = 0; t < 4; ++t)
      bfr[t] = *(const f16x8*)(smem + 8192 + (wn + t * 16 + l16) * 64 + qoff);
#pragma unroll
    for (int mt = 0; mt < 4; ++mt)
#pragma unroll
      for (int nt = 0; nt < 4; ++nt)
        acc[mt][nt] = __builtin_amdgcn_mfma_f32_16x16x32_f16(af[mt], bfr[nt], acc[mt][nt], 0, 0, 0);
    __syncthreads();

    ag0 += BK; ag1 += BK; qw += 4; wbhp += BK;
  }

#pragma unroll
  for (int mt = 0; mt < 4; ++mt) {
    const int rowb = m0 + wm + mt * 16 + quad * 4;
    int tk[4];
#pragma unroll
    for (int r = 0; r < 4; ++r) tk[r] = inv[rowb + r];
#pragma unroll
    for (int nt = 0; nt < 4; ++nt) {
      const int col = n0 + wn + nt * 16 + l16;
      const float bv = bias[col];
#pragma unroll
      for (int r = 0; r < 4; ++r) {
        if (tk[r] >= 0)
          out[(size_t)tk[r] * NOUT + col] = acc[mt][nt][r] + bv;
      }
    }
  }
}

extern "C" void kernel_launch(void* const* d_in, const int* in_sizes, int n_in,
                              void* d_out, int out_size, void* d_ws, size_t ws_size,
                              hipStream_t stream) {
  const float* x    = (const float*)d_in[0];
  const float* wb   = (const float*)d_in[1];
  const float* bias = (const float*)d_in[2];
  const int*   qw0  = (const int*)d_in[3];
  const int*   qw1  = (const int*)d_in[4];
  const int*   qz0  = (const int*)d_in[5];
  const int*   qz1  = (const int*)d_in[6];
  const float* sc0  = (const float*)d_in[7];
  const float* sc1  = (const float*)d_in[8];
  const int*   indices = (const int*)d_in[11];
  float* out = (float*)d_out;

  // workspace: xh [(T_TOK+1)*DIN f16] | inv | meta | weff (128 MB) or wbh (32 MB)
  char* w = (char*)d_ws;
  _Float16* xh = (_Float16*)w;
  size_t off = (size_t)(T_TOK + 1) * DIN * 2;
  int* inv  = (int*)(w + off);
  int* meta = inv + ROWS_PAD;
  size_t woff = (off + (size_t)ROWS_PAD * 4 + 64 + 255) & ~(size_t)255;
  _Float16* wout = (_Float16*)(w + woff);
  const bool full = ws_size >= woff + (size_t)4 * NOUT * DIN * 2;

  const int nprep = 2 + T_TOK + NOUT;   // sort + x rows (+zero) + weight rows
  dim3 g(NOUT / BN, ROWS_PAD / BM, 1);  // 64 x 11

  if (full) {
    prep_all<true><<<nprep, 256, 0, stream>>>(x, wb, qw0, qw1, qz0, qz1, sc0, sc1,
                                              indices, xh, wout, inv, meta);
    kslim<<<g, 256, 0, stream>>>(xh, wout, bias, inv, meta, out);
  } else {
    prep_all<false><<<nprep, 256, 0, stream>>>(x, wb, qw0, qw1, qz0, qz1, sc0, sc1,
                                               indices, xh, wout, inv, meta);
    kdq<<<g, 256, 0, stream>>>(xh, wout, qw0, qw1, qz0, qz1, sc0, sc1,
                               bias, inv, meta, out);
  }
}